// Round 1
// 677.780 us; speedup vs baseline: 1.0138x; 1.0138x over previous
//
#include <hip/hip_runtime.h>
#include <hip/hip_bf16.h>
#include <cstdint>

// AdaAffcell fused kernel for MI355X (gfx950).
// hx = concat(h, x) [k: 0..127 = h, 128..255 = x], K=256.
// alpha = sigmoid(hx @ W_g^T + b_g); z = hx @ W_a^T + b_a
// h_tilde = alpha*tanh(z) + (1-alpha)*z;  out = LayerNorm(h_tilde)*gamma+beta
//
// HBM-bound problem (768 MB min traffic ~122us @6.3TB/s). bf16 MFMA 16x16x32.
// 8 waves/block; wave w owns output cols [16w,16w+16) for BOTH gates, W_a/W_g
// fragments resident in VGPRs. 64-row tiles of hx staged in LDS via a
// 16B-aligned union. Register double-buffer: tile t+1 loads issued before S1.
//
// KEY CHANGE vs prev version: __syncthreads() emits `s_waitcnt vmcnt(0)` which
// force-drained the t+1 prefetch at the very next barrier (S2), exposing a full
// HBM round trip per tile per wave. Replaced with raw s_barrier + lgkmcnt-only
// waits where LDS visibility is needed -> prefetch stays in flight across the
// whole tile body. Also: bf16 pack via v_cvt_pk_bf16_f32 (compiler-fused from
// __float22bfloat162_rn) instead of the ~8-VALU bit-trick per pair.

#define MT         64                       // rows per tile
#define NBLOCKS    1024
#define TILES_PB   8                        // 524288 / 64 / 1024
#define TPB        512                      // 8 waves
#define EPS        1e-5f
#define LDS_STRIDE 264                      // bf16 elems per row (256 + 8 pad)
#define HT_STRIDE  132                      // f32 elems per row for h_tilde

typedef __attribute__((ext_vector_type(8))) short  short8;
typedef __attribute__((ext_vector_type(4))) float  floatx4;

union LdsU {
    unsigned short a[MT][LDS_STRIDE];   // 64*264*2 = 33792 B  (hx tile, bf16)
    float          ht[MT * HT_STRIDE];  // 64*132*4 = 33792 B  (h_tilde, f32)
};

// Raw barriers: NO vmcnt drain (global prefetch survives). lgkmcnt(0) only
// where our own LDS writes must be visible to other waves after the barrier.
// "memory" clobber pins all memory ops on their side of the barrier (rule #18
// concerns register-only ops, which is not what these guard).
#define BAR_LDS()  asm volatile("s_waitcnt lgkmcnt(0)\n\ts_barrier" ::: "memory")
#define BAR_ONLY() asm volatile("s_barrier" ::: "memory")

static __device__ __forceinline__ unsigned pack2(float lo, float hi) {
    // RNE f32->bf16 pair; compiler emits v_cvt_pk_bf16_f32 (1 instr / 2 elems)
    __hip_bfloat162 t = __float22bfloat162_rn(make_float2(lo, hi));
    union { __hip_bfloat162 b; unsigned u; } v; v.b = t;
    return v.u;   // lo in low 16 bits, hi in high 16 bits
}

static __device__ __forceinline__ short8 load_wfrag(const float* __restrict__ w) {
    union { short8 s; uint4 u; } r;
    r.u.x = pack2(w[0], w[1]);
    r.u.y = pack2(w[2], w[3]);
    r.u.z = pack2(w[4], w[5]);
    r.u.w = pack2(w[6], w[7]);
    return r.s;
}

__global__ __launch_bounds__(TPB, 2)
void adaff_kernel(const float* __restrict__ x,  const float* __restrict__ h,
                  const float* __restrict__ Wa, const float* __restrict__ Wg,
                  const float* __restrict__ ba_p, const float* __restrict__ bg_p,
                  const float* __restrict__ gamma, const float* __restrict__ beta,
                  float* __restrict__ out)
{
    __shared__ __align__(16) LdsU S;

    const int tid  = threadIdx.x;
    const int wave = tid >> 6;
    const int lane = tid & 63;
    const int q    = lane >> 4;     // quad 0..3
    const int n    = lane & 15;
    const int col  = wave * 16 + n; // output h-index this lane epilogues

    // ---- B fragments (weights) resident in registers, loaded once (L2-hot).
    // B-operand layout for mfma_f32_16x16x32_bf16: lane(n,q) holds
    // B[k = kt*32 + q*8 + j][n] = W[n][kt*32 + q*8 + j].
    short8 bfa[8], bfg[8];
    #pragma unroll
    for (int kt = 0; kt < 8; ++kt) {
        bfa[kt] = load_wfrag(Wa + (size_t)col * 256 + kt * 32 + q * 8);
        bfg[kt] = load_wfrag(Wg + (size_t)col * 256 + kt * 32 + q * 8);
    }
    const float bias_a = ba_p[col];
    const float bias_g = bg_p[col];
    const float2 gam2 = *(const float2*)(gamma + 2 * lane);
    const float2 bet2 = *(const float2*)(beta  + 2 * lane);

    const float4* h4 = (const float4*)h;
    const float4* x4 = (const float4*)x;

    const size_t tile0 = (size_t)blockIdx.x * TILES_PB;

    // staging: 64 rows * 32 float4/row = 2048 float4 per source; 4 per thread
    int srow[4], sc4[4];
    #pragma unroll
    for (int i = 0; i < 4; ++i) {
        int idx = i * TPB + tid;
        srow[i] = idx >> 5;
        sc4[i]  = idx & 31;
    }

    // prologue: load tile 0 into regs
    float4 sh[4], sx[4];
    {
        size_t r0 = tile0 * MT;
        #pragma unroll
        for (int i = 0; i < 4; ++i) {
            sh[i] = h4[(r0 + srow[i]) * 32 + sc4[i]];
            sx[i] = x4[(r0 + srow[i]) * 32 + sc4[i]];
        }
    }

    for (int t = 0; t < TILES_PB; ++t) {
        const size_t r0 = (tile0 + t) * MT;

        // 1) staged regs -> LDS (v_cvt_pk_bf16_f32 pairs)
        #pragma unroll
        for (int i = 0; i < 4; ++i) {
            uint2 hh, xx;
            hh.x = pack2(sh[i].x, sh[i].y); hh.y = pack2(sh[i].z, sh[i].w);
            xx.x = pack2(sx[i].x, sx[i].y); xx.y = pack2(sx[i].z, sx[i].w);
            *(uint2*)&S.a[srow[i]][      sc4[i] * 4] = hh;   // 8B aligned
            *(uint2*)&S.a[srow[i]][128 + sc4[i] * 4] = xx;
        }

        // 2) issue next tile's global loads BEFORE the barrier; they stay in
        //    flight across S1..S4 (no vmcnt drain) and are only awaited by the
        //    compiler-inserted vmcnt at their use in pack(t+1).
        if (t + 1 < TILES_PB) {
            size_t r1 = (tile0 + t + 1) * MT;
            #pragma unroll
            for (int i = 0; i < 4; ++i) {
                sh[i] = h4[(r1 + srow[i]) * 32 + sc4[i]];
                sx[i] = x4[(r1 + srow[i]) * 32 + sc4[i]];
            }
        }
        BAR_LDS();   // S1: hx tile visible to all waves

        // 3) MFMA: 4 M-subtiles x 2 gates, K = 8 k-tiles of 32.
        //    A-frag: lane(n,q) holds A[m = mt*16 + n][k = kt*32 + q*8 + j].
        floatx4 accz[4] = {}, accg[4] = {};
        #pragma unroll
        for (int kt = 0; kt < 8; ++kt) {
            short8 a[4];
            #pragma unroll
            for (int m = 0; m < 4; ++m)
                a[m] = *(const short8*)&S.a[m * 16 + n][kt * 32 + q * 8]; // 16B aligned
            #pragma unroll
            for (int m = 0; m < 4; ++m) {
                accz[m] = __builtin_amdgcn_mfma_f32_16x16x32_bf16(a[m], bfa[kt], accz[m], 0, 0, 0);
                accg[m] = __builtin_amdgcn_mfma_f32_16x16x32_bf16(a[m], bfg[kt], accg[m], 0, 0, 0);
            }
        }

        // 4) epilogue in regs: bias, sigmoid, tanh, blend
        float htv[4][4];
        #pragma unroll
        for (int m = 0; m < 4; ++m) {
            #pragma unroll
            for (int i = 0; i < 4; ++i) {
                float z = accz[m][i] + bias_a;
                float g = accg[m][i] + bias_g;
                float al = 1.f / (1.f + __expf(-g));
                float zc = fminf(fmaxf(z, -15.f), 15.f);
                float e  = __expf(-2.f * zc);
                float th = (1.f - e) / (1.f + e);
                htv[m][i] = z + al * (th - z);
            }
        }
        // All waves' a-frag ds_reads were consumed by their MFMAs (compiler
        // lgkmcnt) before arrival -> bare barrier suffices to reuse the union.
        BAR_ONLY();  // S2

        // 5) h_tilde -> LDS (f32 view of the union) for cross-wave LayerNorm.
        //    C/D layout: col = lane&15, row = quad*4 + reg.
        #pragma unroll
        for (int m = 0; m < 4; ++m) {
            #pragma unroll
            for (int i = 0; i < 4; ++i)
                S.ht[(m * 16 + q * 4 + i) * HT_STRIDE + col] = htv[m][i];
        }
        BAR_LDS();   // S3: h_tilde visible

        // 6) LayerNorm: wave handles 8 rows; 2 elems/lane; 64-lane xor reduce
        #pragma unroll
        for (int rr = 0; rr < 8; ++rr) {
            int r = wave * 8 + rr;
            float2 v = *(const float2*)&S.ht[r * HT_STRIDE + 2 * lane];  // 8B aligned
            float s  = v.x + v.y;
            float ss = v.x * v.x + v.y * v.y;
            #pragma unroll
            for (int off = 32; off > 0; off >>= 1) {
                s  += __shfl_xor(s,  off, 64);
                ss += __shfl_xor(ss, off, 64);
            }
            float mean = s * (1.f / 128.f);
            float var  = ss * (1.f / 128.f) - mean * mean;
            float rstd = rsqrtf(var + EPS);
            float2 o;
            o.x = (v.x - mean) * rstd * gam2.x + bet2.x;
            o.y = (v.y - mean) * rstd * gam2.y + bet2.y;
            *(float2*)(out + (r0 + r) * 128 + 2 * lane) = o;
        }
        // LN reads retired per-wave before arrival -> bare barrier guards the
        // next iteration's pack writes into S.a.
        BAR_ONLY();  // S4
    }
}

extern "C" void kernel_launch(void* const* d_in, const int* in_sizes, int n_in,
                              void* d_out, int out_size, void* d_ws, size_t ws_size,
                              hipStream_t stream) {
    const float* x     = (const float*)d_in[0];
    const float* h     = (const float*)d_in[1];
    const float* Wa    = (const float*)d_in[2];
    const float* Wg    = (const float*)d_in[3];
    const float* ba    = (const float*)d_in[4];
    const float* bg    = (const float*)d_in[5];
    const float* gamma = (const float*)d_in[6];
    const float* beta  = (const float*)d_in[7];
    float* out = (float*)d_out;

    adaff_kernel<<<NBLOCKS, TPB, 0, stream>>>(x, h, Wa, Wg, ba, bg, gamma, beta, out);
}